// Round 15
// baseline (179.305 us; speedup 1.0000x reference)
//
#include <hip/hip_runtime.h>
#include <math.h>

// ---------------------------------------------------------------------------
// RNN_6451040879094  (B=4096, I=H=1024, O=4096, fp32 in/out)
// R15: gemm2p_body -> double-buffered BK=64 (48KB LDS, 3 blocks/CU):
//      stage k+1 into buf^1 at top of step k; ONE vmcnt(0)+barrier per
//      K-step (R7's proven pattern, which gave gemm8p 90->70). Staging
//      latency hides under step k's 12 ds_reads + 16 MFMAs.
//      gemm8p locked (R13/R14 form, bf16 logits). f2b, softmax unchanged.
// d_out: out(4096*4096) ++ h0(4096*1024) ++ h1(4096*1024), fp32.
// ---------------------------------------------------------------------------

typedef __attribute__((ext_vector_type(8))) short bf16x8;
typedef __attribute__((ext_vector_type(4))) float f32x4;

__device__ __forceinline__ unsigned short f2b_rne(float f) {
    unsigned int x = __float_as_uint(f);
    x += 0x7FFF + ((x >> 16) & 1);
    return (unsigned short)(x >> 16);
}

__device__ __forceinline__ void gload_lds16(const void* g, void* l) {
    __builtin_amdgcn_global_load_lds(
        (const __attribute__((address_space(1))) void*)g,
        (__attribute__((address_space(3))) void*)l,
        16, 0, 0);
}

// ---------------- fp32 -> bf16 conversion (8 segments) ----------------------
struct CvtSeg { const float* src; unsigned short* dst; unsigned n8; };
struct CvtArgs { CvtSeg seg[8]; };

__global__ __launch_bounds__(256) void f2b_multi(CvtArgs a)
{
    unsigned i = blockIdx.x * 256u + threadIdx.x;
#pragma unroll
    for (int s = 0; s < 8; ++s) {
        if (i < a.seg[s].n8) {
            const float4* src = (const float4*)a.seg[s].src;
            float4 u = src[2 * (size_t)i];
            float4 v = src[2 * (size_t)i + 1];
            unsigned short t[8] = {
                f2b_rne(u.x), f2b_rne(u.y), f2b_rne(u.z), f2b_rne(u.w),
                f2b_rne(v.x), f2b_rne(v.y), f2b_rne(v.z), f2b_rne(v.w)};
            *(uint4*)(a.seg[s].dst + 8 * (size_t)i) = *(const uint4*)t;
            return;
        }
        i -= a.seg[s].n8;
    }
}

// ============ double-buffered BK=64 2-phase GEMM body (GEMM1 / GEMM2) =======
// LDS: As[2][BM][64], Ws[2][BN][64] bf16. Chunk swizzle: LDS chunk cc of
// row r holds global k-chunk (cc^r)&7; frag read at fk^(r&7), kk=1 at ^4.
// SYNC (R7 pattern): stage step kk+1 into buf^1 at top of step kk; reads
// and MFMA on buf; ONE vmcnt(0)+s_barrier per K-step. Stage-overwrite of
// buf(kk-1) is safe: its readers' lgkm waits precede MFMAs which precede
// barrier(kk-1), and stages are issued after that barrier.
struct GemmP {
    const unsigned short *Aa, *Ab; int lda;
    const unsigned short *Wa, *Wb; int ldw;
    const float *ba, *bb;
    float* C; int ldc;
    unsigned short* Cb; int ldcb;
    int nx, nb, do_tanh;
};

template<int BM, int BN>
__device__ __forceinline__ void gemm2p_body(
    const GemmP& p, int bid0, unsigned short* As, unsigned short* Ws, int tid)
{
    constexpr int FM = BM / 32;
    constexpr int FN = BN / 32;
    constexpr int ASZ = BM * 64;
    constexpr int WSZ = BN * 64;
    int bid = (bid0 & 7) * (p.nb >> 3) + (bid0 >> 3);
    const int row0 = (bid / p.nx) * BM;
    const int col0 = (bid % p.nx) * BN;

    const int wid = tid >> 6, lane = tid & 63;
    const int wr = wid >> 1, wc = wid & 1;
    const int fr = lane & 15, fk = lane >> 4;

    f32x4 acc[FM][FN] = {};

#define STAGE2P(kk, b) {                                                      \
    const unsigned short* A_ = ((kk) < 16) ? p.Aa : p.Ab;                     \
    const unsigned short* W_ = ((kk) < 16) ? p.Wa : p.Wb;                     \
    const int k0_ = ((kk) & 15) << 6;                                         \
    unsigned short* Ad_ = As + (b) * ASZ;                                     \
    unsigned short* Wd_ = Ws + (b) * WSZ;                                     \
    _Pragma("unroll") for (int i = 0; i < BM / 32; ++i) {                     \
        int c = i * 256 + wid * 64 + lane;                                    \
        int r = c >> 3, cc = c & 7;                                           \
        int gk = k0_ + (((cc ^ r) & 7) << 3);                                 \
        gload_lds16(A_ + (size_t)(row0 + r) * p.lda + gk,                     \
                    Ad_ + (i * 256 + wid * 64) * 8);                          \
    }                                                                         \
    _Pragma("unroll") for (int i = 0; i < BN / 32; ++i) {                     \
        int c = i * 256 + wid * 64 + lane;                                    \
        int r = c >> 3, cc = c & 7;                                           \
        int gk = k0_ + (((cc ^ r) & 7) << 3);                                 \
        gload_lds16(W_ + (size_t)(col0 + r) * p.ldw + gk,                     \
                    Wd_ + (i * 256 + wid * 64) * 8);                          \
    } }

    // prologue: stage step 0 into buf0, drain, barrier
    STAGE2P(0, 0);
    asm volatile("s_waitcnt vmcnt(0)" ::: "memory");
    __builtin_amdgcn_s_barrier();

    for (int kk = 0; kk < 32; ++kk) {
        const int cur = kk & 1;
        if (kk + 1 < 32) STAGE2P(kk + 1, cur ^ 1);
        const unsigned short* Ab_ = As + cur * ASZ;
        const unsigned short* Wb_ = Ws + cur * WSZ;

        bf16x8 af[FM][2], wf[FN][2];
#pragma unroll
        for (int m = 0; m < FM; ++m) {
            int r = wr * (BM / 2) + m * 16 + fr;
            int cc = fk ^ (r & 7);
            af[m][0] = *(const bf16x8*)&Ab_[r * 64 + cc * 8];
            af[m][1] = *(const bf16x8*)&Ab_[r * 64 + (cc ^ 4) * 8];
        }
#pragma unroll
        for (int n = 0; n < FN; ++n) {
            int r = wc * (BN / 2) + n * 16 + fr;
            int cc = fk ^ (r & 7);
            wf[n][0] = *(const bf16x8*)&Wb_[r * 64 + cc * 8];
            wf[n][1] = *(const bf16x8*)&Wb_[r * 64 + (cc ^ 4) * 8];
        }
#pragma unroll
        for (int m = 0; m < FM; ++m)
#pragma unroll
            for (int n = 0; n < FN; ++n) {
                acc[m][n] = __builtin_amdgcn_mfma_f32_16x16x32_bf16(
                    af[m][0], wf[n][0], acc[m][n], 0, 0, 0);
                acc[m][n] = __builtin_amdgcn_mfma_f32_16x16x32_bf16(
                    af[m][1], wf[n][1], acc[m][n], 0, 0, 0);
            }
        // one drain + barrier per K-step (stages of kk+1 complete here)
        asm volatile("s_waitcnt vmcnt(0)" ::: "memory");
        __builtin_amdgcn_s_barrier();
    }
#undef STAGE2P

    const bool dot = p.do_tanh != 0;
#pragma unroll
    for (int n = 0; n < FN; ++n) {
        const int col = col0 + wc * (BN / 2) + n * 16 + fr;
        float b = p.ba[col];
        if (p.bb) b += p.bb[col];
#pragma unroll
        for (int m = 0; m < FM; ++m) {
#pragma unroll
            for (int j = 0; j < 4; ++j) {
                const int r = row0 + wr * (BM / 2) + m * 16 + fk * 4 + j;
                float v = acc[m][n][j] + b;
                if (dot) v = tanhf(v);
                p.C[(size_t)r * p.ldc + col] = v;
                if (p.Cb) p.Cb[(size_t)r * p.ldcb + col] = f2b_rne(v);
            }
        }
    }
}

__global__ __launch_bounds__(256) void gemm1_k(GemmP p)
{
    __shared__ __align__(16) unsigned short As[2 * 128 * 64];
    __shared__ __align__(16) unsigned short Ws[2 * 64 * 64];
    gemm2p_body<128, 64>(p, blockIdx.x, As, Ws, threadIdx.x);
}

// ---------------- row log_softmax (bf16-in, fp32-out) -----------------------
__device__ __forceinline__ void logsoftmax_row_b16(
    const unsigned short* __restrict__ lb, float* __restrict__ op, int tid)
{
    const int lane = tid & 63;
    const int wv = tid >> 6;
    __shared__ float redm[4];
    __shared__ float reds[4];

    uint4 r[2];
    r[0] = *(const uint4*)&lb[tid * 8];
    r[1] = *(const uint4*)&lb[2048 + tid * 8];
    float v[16];
#pragma unroll
    for (int h = 0; h < 2; ++h)
#pragma unroll
        for (int j = 0; j < 4; ++j) {
            unsigned u = ((const unsigned*)&r[h])[j];
            v[h * 8 + 2 * j]     = __uint_as_float(u << 16);
            v[h * 8 + 2 * j + 1] = __uint_as_float(u & 0xFFFF0000u);
        }

    float m = v[0];
#pragma unroll
    for (int i = 1; i < 16; ++i) m = fmaxf(m, v[i]);
#pragma unroll
    for (int off = 32; off; off >>= 1) m = fmaxf(m, __shfl_xor(m, off));
    if (lane == 0) redm[wv] = m;
    __syncthreads();
    m = fmaxf(fmaxf(redm[0], redm[1]), fmaxf(redm[2], redm[3]));

    float s = 0.f;
#pragma unroll
    for (int i = 0; i < 16; ++i) s += expf(v[i] - m);
#pragma unroll
    for (int off = 32; off; off >>= 1) s += __shfl_xor(s, off);
    if (lane == 0) reds[wv] = s;
    __syncthreads();
    s = reds[0] + reds[1] + reds[2] + reds[3];

    const float lse = m + logf(s);
#pragma unroll
    for (int h = 0; h < 2; ++h) {
        float4 o0, o1;
        o0.x = v[h*8+0]-lse; o0.y = v[h*8+1]-lse; o0.z = v[h*8+2]-lse; o0.w = v[h*8+3]-lse;
        o1.x = v[h*8+4]-lse; o1.y = v[h*8+5]-lse; o1.z = v[h*8+6]-lse; o1.w = v[h*8+7]-lse;
        *(float4*)&op[h * 2048 + tid * 8]     = o0;
        *(float4*)&op[h * 2048 + tid * 8 + 4] = o1;
    }
}

// GEMM2 at 128x64/BK64-dbuf (blocks 0..511) + log_softmax rows (512..4607)
__global__ __launch_bounds__(256) void g2sm_k(
    GemmP p, float* __restrict__ out, const unsigned short* __restrict__ lb16)
{
    if (blockIdx.x < 512) {
        __shared__ __align__(16) unsigned short As[2 * 128 * 64];
        __shared__ __align__(16) unsigned short Ws[2 * 64 * 64];
        gemm2p_body<128, 64>(p, blockIdx.x, As, Ws, threadIdx.x);
    } else {
        const int row = blockIdx.x - 512;
        logsoftmax_row_b16(lb16 + (size_t)row * 4096,
                           out + (size_t)row * 4096, threadIdx.x);
    }
}

// ============ per-phase counted 256x256 GEMM (GEMM3) — locked ===============
// Schedule: p0 vmcnt(4);bar;rd af0,wfA;st A0(t+1);Q00 | p1 ...B1(t)... |
// p2 ...A1(t)... | p3 no-bar st A1(t+1) Q10. Tail 4/2/0. bf16 logits out.

__device__ __forceinline__ void stage_half8(
    const unsigned short* __restrict__ src, int ld, int base_rc, int tau, int h,
    unsigned short* lds, int wid, int lane, bool isA)
{
    unsigned short* dst = lds + (tau & 1) * 16384 + h * 8192 + wid * 1024;
    const int k0 = (tau & 15) << 6;
#pragma unroll
    for (int i = 0; i < 2; ++i) {
        int c = wid * 128 + i * 64 + lane;
        int ir = c >> 3, cc = c & 7;
        int grow = isA ? (base_rc + h * 64 + (ir & 63) + ((ir >> 6) << 7))
                       : (base_rc + h * 32 + (ir & 31) + ((ir >> 5) << 6));
        int gk = k0 + (((cc ^ ir) & 7) << 3);
        gload_lds16(src + (size_t)grow * ld + gk, dst + i * 512);
    }
}

__global__ __launch_bounds__(512, 2) void gemm8p(
    const unsigned short* __restrict__ Aa, const unsigned short* __restrict__ Ab,
    const unsigned short* __restrict__ Wa, const unsigned short* __restrict__ Wb,
    int lda, int ldw, const float* __restrict__ bias,
    unsigned short* __restrict__ Cb16, int ldc, int nx)
{
    constexpr int NT = 32;
    __shared__ __align__(16) unsigned short smem[65536];   // 128 KB
    unsigned short* As = smem;
    unsigned short* Bs = smem + 32768;

    int bid = blockIdx.x;
    bid = (bid & 7) * 32 + (bid >> 3);            // XCD swizzle (256 = 8*32)
    const int row0 = (bid / nx) * 256;
    const int col0 = (bid % nx) * 256;

    const int tid = threadIdx.x;
    const int wid = tid >> 6, lane = tid & 63;
    const int wr = wid >> 2, wc = wid & 3;        // 2 x 4 wave grid
    const int fr = lane & 15, fk = lane >> 4;
    const int ch0 = fk ^ (fr & 7);
    const int ch1 = ch0 ^ 4;

#define STA8(tau, h) stage_half8(((tau) < 16 ? Aa : Ab), lda, row0, (tau), (h), As, wid, lane, true)
#define STB8(tau, h) stage_half8(((tau) < 16 ? Wa : Wb), ldw, col0, (tau), (h), Bs, wid, lane, false)

#define LDAF(QM) { const unsigned short* Ap_ = Abase + (QM) * 8192;           \
    _Pragma("unroll") for (int mf = 0; mf < 4; ++mf) {                        \
        int ia = wr * 64 + mf * 16 + fr;                                      \
        af[mf][0] = *(const bf16x8*)&Ap_[ia * 64 + ch0 * 8];                  \
        af[mf][1] = *(const bf16x8*)&Ap_[ia * 64 + ch1 * 8]; } }

#define LDWF(QN, WF) { const unsigned short* Bp_ = Bbase + (QN) * 8192;       \
    _Pragma("unroll") for (int nf = 0; nf < 2; ++nf) {                        \
        int ib = wc * 32 + nf * 16 + fr;                                      \
        WF[nf][0] = *(const bf16x8*)&Bp_[ib * 64 + ch0 * 8];                  \
        WF[nf][1] = *(const bf16x8*)&Bp_[ib * 64 + ch1 * 8]; } }

#define MMQ(QM, QN, WF) {                                                     \
    __builtin_amdgcn_s_setprio(1);                                            \
    _Pragma("unroll") for (int mf = 0; mf < 4; ++mf)                          \
    _Pragma("unroll") for (int nf = 0; nf < 2; ++nf) {                        \
        acc[QM][QN][mf][nf] = __builtin_amdgcn_mfma_f32_16x16x32_bf16(        \
            af[mf][0], WF[nf][0], acc[QM][QN][mf][nf], 0, 0, 0);              \
        acc[QM][QN][mf][nf] = __builtin_amdgcn_mfma_f32_16x16x32_bf16(        \
            af[mf][1], WF[nf][1], acc[QM][QN][mf][nf], 0, 0, 0); }            \
    __builtin_amdgcn_s_setprio(0); }

    f32x4 acc[2][2][4][2] = {};
    bf16x8 af[4][2], wfA[2][2], wfB[2][2];

    // prologue: stage tile0's halves in consumption order A0,B0,B1,A1
    STA8(0, 0); STB8(0, 0); STB8(0, 1); STA8(0, 1);

    for (int t = 0; t < NT; ++t) {
        const unsigned short* Abase = As + (t & 1) * 16384;
        const unsigned short* Bbase = Bs + (t & 1) * 16384;
        const bool more = (t + 1 < NT);

        // p0: Q(0,0) — consumes A0(t),B0(t)
        asm volatile("s_waitcnt vmcnt(4)" ::: "memory");
        __builtin_amdgcn_s_barrier();
        LDAF(0); LDWF(0, wfA);
        if (more) STA8(t + 1, 0);
        MMQ(0, 0, wfA);

        // p1: Q(0,1) — consumes B1(t)
        if (more) { asm volatile("s_waitcnt vmcnt(4)" ::: "memory"); }
        else      { asm volatile("s_waitcnt vmcnt(2)" ::: "memory"); }
        __builtin_amdgcn_s_barrier();
        LDWF(1, wfB);
        if (more) STB8(t + 1, 0);
        MMQ(0, 1, wfB);

        // p2: Q(1,1) — consumes A1(t)
        if (more) { asm volatile("s_waitcnt vmcnt(4)" ::: "memory"); }
        else      { asm volatile("s_waitcnt vmcnt(0)" ::: "memory"); }
        __builtin_amdgcn_s_barrier();
        LDAF(1);
        if (more) STB8(t + 1, 1);
        MMQ(1, 1, wfB);

        // p3: Q(1,0) — zero ds_reads, no barrier
        if (more) STA8(t + 1, 1);
        MMQ(1, 0, wfA);
    }
#undef MMQ
#undef LDAF
#undef LDWF
#undef STA8
#undef STB8

    // epilogue: acc -> LDS (fp32, +bias, XOR de-conflict) -> bf16 ushort4
    float bv[2][2];
#pragma unroll
    for (int qn = 0; qn < 2; ++qn)
#pragma unroll
        for (int nf = 0; nf < 2; ++nf)
            bv[qn][nf] = bias[col0 + wc * 64 + qn * 32 + nf * 16 + fr];

    float* Ct = (float*)smem;                     // [128][256] fp32 = 128KB
    __syncthreads();
#pragma unroll
    for (int qm = 0; qm < 2; ++qm) {
        if (qm) __syncthreads();
#pragma unroll
        for (int qn = 0; qn < 2; ++qn)
#pragma unroll
            for (int nf = 0; nf < 2; ++nf) {
                const int col = wc * 64 + qn * 32 + nf * 16 + fr;
#pragma unroll
                for (int mf = 0; mf < 4; ++mf)
#pragma unroll
                    for (int j = 0; j < 4; ++j) {
                        int lr = wr * 64 + mf * 16 + fk * 4 + j;
                        int pc = col ^ (((lr >> 2) & 3) << 4);
                        Ct[lr * 256 + pc] = acc[qm][qn][mf][nf][j] + bv[qn][nf];
                    }
            }
        __syncthreads();
#pragma unroll
        for (int k = 0; k < 16; ++k) {
            int idx = k * 512 + tid;
            int lrow = idx >> 6, c4 = idx & 63;
            int pc4 = (c4 * 4) ^ (((lrow >> 2) & 3) << 4);
            int grow = row0 + qm * 64 + (lrow & 63) + ((lrow >> 6) << 7);
            float4 v = *(const float4*)&Ct[lrow * 256 + pc4];
            unsigned short o[4] = { f2b_rne(v.x), f2b_rne(v.y),
                                    f2b_rne(v.z), f2b_rne(v.w) };
            *(ushort4*)&Cb16[(size_t)grow * ldc + col0 + c4 * 4] =
                *(const ushort4*)o;
        }
    }
}

// ============================================================================
extern "C" void kernel_launch(void* const* d_in, const int* in_sizes, int n_in,
                              void* d_out, int out_size, void* d_ws, size_t ws_size,
                              hipStream_t stream)
{
    (void)in_sizes; (void)n_in; (void)out_size; (void)ws_size;

    const float* input  = (const float*)d_in[0];
    const float* hidden = (const float*)d_in[1];
    const float* b_ih0  = (const float*)d_in[4];
    const float* b_hh0  = (const float*)d_in[5];
    const float* b_ih1  = (const float*)d_in[8];
    const float* b_hh1  = (const float*)d_in[9];
    const float* b_out  = (const float*)d_in[11];

    float* out = (float*)d_out;                    // [4096,4096]
    float* h0  = out + (size_t)4096 * 4096;
    float* h1  = h0 + (size_t)4096 * 1024;

    unsigned short* xb    = (unsigned short*)d_ws;
    unsigned short* hidb  = xb    + (size_t)4096 * 1024;
    unsigned short* h0b   = hidb  + (size_t)2 * 4096 * 1024;
    unsigned short* Wih0b = h0b   + (size_t)4096 * 1024;
    unsigned short* Whh0b = Wih0b + (size_t)1024 * 1024;
    unsigned short* Wih1b = Whh0b + (size_t)1024 * 1024;
    unsigned short* Whh1b = Wih1b + (size_t)1024 * 1024;
    unsigned short* Woutb = Whh1b + (size_t)1024 * 1024;
    unsigned short* lb16  = Woutb + (size_t)4096 * 2048;   // bf16 logits, 32MB
    unsigned short* hid0b = hidb;
    unsigned short* hid1b = hidb + (size_t)4096 * 1024;

    // one standalone conversion pass
    CvtArgs ca;
    ca.seg[0] = { input,                 xb,    524288u };
    ca.seg[1] = { hidden,                hidb, 1048576u };
    ca.seg[2] = { (const float*)d_in[2], Wih0b, 131072u };
    ca.seg[3] = { (const float*)d_in[3], Whh0b, 131072u };
    ca.seg[4] = { (const float*)d_in[6], Wih1b, 131072u };
    ca.seg[5] = { (const float*)d_in[7], Whh1b, 131072u };
    ca.seg[6] = { (const float*)d_in[10],Woutb, 1048576u };
    ca.seg[7] = { nullptr, nullptr, 0u };
    hipLaunchKernelGGL(f2b_multi, dim3(12288), dim3(256), 0, stream, ca);

    // GEMM1: h0 = tanh(x@Wih0^T + hid0@Whh0^T + b), 128x64/BK64-dbuf
    GemmP p1;
    p1.Aa = xb;    p1.Ab = hid0b; p1.lda = 1024;
    p1.Wa = Wih0b; p1.Wb = Whh0b; p1.ldw = 1024;
    p1.ba = b_ih0; p1.bb = b_hh0;
    p1.C = h0; p1.ldc = 1024; p1.Cb = h0b; p1.ldcb = 1024;
    p1.nx = 16; p1.nb = 512; p1.do_tanh = 1;
    hipLaunchKernelGGL(gemm1_k, dim3(512), dim3(256), 0, stream, p1);

    // GEMM3: bf16 logits = x@W_out[:,:1024]^T + h0@W_out[:,1024:]^T + b_out
    hipLaunchKernelGGL(gemm8p, dim3(256), dim3(512), 0, stream,
                       xb, h0b, Woutb, Woutb + 1024, 1024, 2048,
                       b_out, lb16, 4096, 16);

    // GEMM2 at 128x64/BK64-dbuf (512 blocks) + log_softmax (4096 rows)
    GemmP p2;
    p2.Aa = h0b;   p2.Ab = hid1b; p2.lda = 1024;
    p2.Wa = Wih1b; p2.Wb = Whh1b; p2.ldw = 1024;
    p2.ba = b_ih1; p2.bb = b_hh1;
    p2.C = h1; p2.ldc = 1024; p2.Cb = nullptr; p2.ldcb = 0;
    p2.nx = 16; p2.nb = 512; p2.do_tanh = 1;
    hipLaunchKernelGGL(g2sm_k, dim3(4608), dim3(256), 0, stream, p2, out, lb16);
}

// Round 16
// 159.279 us; speedup vs baseline: 1.1257x; 1.1257x over previous
//
#include <hip/hip_runtime.h>
#include <math.h>

// ---------------------------------------------------------------------------
// RNN_6451040879094  (B=4096, I=H=1024, O=4096, fp32 in/out)
// R16: REVERT to R14 (measured best, 162.2us). R15's dbuf bodies cut
//      occupancy 6->3 blocks/CU (24->48KB LDS) and regressed; the 2-phase
//      bodies rely on cross-block TLP, not intra-block ILP (m99/m100).
//      Structure: f2b (8-seg) -> gemm1 (128x64/BK64, 512blk) ->
//      gemm8p (256^2 4-phase counted, bf16-logits, locked) ->
//      g2sm (GEMM2 128x64/BK64 + bf16-in softmax).
// d_out: out(4096*4096) ++ h0(4096*1024) ++ h1(4096*1024), fp32.
// ---------------------------------------------------------------------------

typedef __attribute__((ext_vector_type(8))) short bf16x8;
typedef __attribute__((ext_vector_type(4))) float f32x4;

__device__ __forceinline__ unsigned short f2b_rne(float f) {
    unsigned int x = __float_as_uint(f);
    x += 0x7FFF + ((x >> 16) & 1);
    return (unsigned short)(x >> 16);
}

__device__ __forceinline__ void gload_lds16(const void* g, void* l) {
    __builtin_amdgcn_global_load_lds(
        (const __attribute__((address_space(1))) void*)g,
        (__attribute__((address_space(3))) void*)l,
        16, 0, 0);
}

// ---------------- fp32 -> bf16 conversion (8 segments) ----------------------
struct CvtSeg { const float* src; unsigned short* dst; unsigned n8; };
struct CvtArgs { CvtSeg seg[8]; };

__global__ __launch_bounds__(256) void f2b_multi(CvtArgs a)
{
    unsigned i = blockIdx.x * 256u + threadIdx.x;
#pragma unroll
    for (int s = 0; s < 8; ++s) {
        if (i < a.seg[s].n8) {
            const float4* src = (const float4*)a.seg[s].src;
            float4 u = src[2 * (size_t)i];
            float4 v = src[2 * (size_t)i + 1];
            unsigned short t[8] = {
                f2b_rne(u.x), f2b_rne(u.y), f2b_rne(u.z), f2b_rne(u.w),
                f2b_rne(v.x), f2b_rne(v.y), f2b_rne(v.z), f2b_rne(v.w)};
            *(uint4*)(a.seg[s].dst + 8 * (size_t)i) = *(const uint4*)t;
            return;
        }
        i -= a.seg[s].n8;
    }
}

// ================= 2-phase BK=64 GEMM body (GEMM1 / GEMM2 roles) ============
// LDS: As[BM][64], Ws[BN][64] bf16; chunk swizzle: LDS chunk cc of row r
// holds global k-chunk (cc^r)&7. Frag read: k-group fk at chunk fk^(r&7),
// kk=1 at ^4. 32 K-steps for K=2048. Single-buffered: cross-block TLP
// (6 blocks/CU at 24KB) hides the staging drain.
struct GemmP {
    const unsigned short *Aa, *Ab; int lda;
    const unsigned short *Wa, *Wb; int ldw;
    const float *ba, *bb;
    float* C; int ldc;
    unsigned short* Cb; int ldcb;
    int nx, nb, do_tanh;
};

template<int BM, int BN>
__device__ __forceinline__ void gemm2p_body(
    const GemmP& p, int bid0, unsigned short* As, unsigned short* Ws, int tid)
{
    constexpr int FM = BM / 32;
    constexpr int FN = BN / 32;
    int bid = (bid0 & 7) * (p.nb >> 3) + (bid0 >> 3);
    const int row0 = (bid / p.nx) * BM;
    const int col0 = (bid % p.nx) * BN;

    const int wid = tid >> 6, lane = tid & 63;
    const int wr = wid >> 1, wc = wid & 1;
    const int fr = lane & 15, fk = lane >> 4;

    f32x4 acc[FM][FN] = {};

    for (int h = 0; h < 2; ++h) {
        const unsigned short* A = h ? p.Ab : p.Aa;
        const unsigned short* W = h ? p.Wb : p.Wa;
        for (int k0 = 0; k0 < 1024; k0 += 64) {
#pragma unroll
            for (int i = 0; i < BM / 32; ++i) {
                int c = i * 256 + wid * 64 + lane;
                int r = c >> 3, cc = c & 7;
                int gk = k0 + (((cc ^ r) & 7) << 3);
                gload_lds16(A + (size_t)(row0 + r) * p.lda + gk,
                            As + (i * 256 + wid * 64) * 8);
            }
#pragma unroll
            for (int i = 0; i < BN / 32; ++i) {
                int c = i * 256 + wid * 64 + lane;
                int r = c >> 3, cc = c & 7;
                int gk = k0 + (((cc ^ r) & 7) << 3);
                gload_lds16(W + (size_t)(col0 + r) * p.ldw + gk,
                            Ws + (i * 256 + wid * 64) * 8);
            }
            __syncthreads();   // full vmcnt(0)+lgkmcnt(0) drain + barrier

            bf16x8 af[FM][2], wf[FN][2];
#pragma unroll
            for (int m = 0; m < FM; ++m) {
                int r = wr * (BM / 2) + m * 16 + fr;
                int cc = fk ^ (r & 7);
                af[m][0] = *(const bf16x8*)&As[r * 64 + cc * 8];
                af[m][1] = *(const bf16x8*)&As[r * 64 + (cc ^ 4) * 8];
            }
#pragma unroll
            for (int n = 0; n < FN; ++n) {
                int r = wc * (BN / 2) + n * 16 + fr;
                int cc = fk ^ (r & 7);
                wf[n][0] = *(const bf16x8*)&Ws[r * 64 + cc * 8];
                wf[n][1] = *(const bf16x8*)&Ws[r * 64 + (cc ^ 4) * 8];
            }
#pragma unroll
            for (int m = 0; m < FM; ++m)
#pragma unroll
                for (int n = 0; n < FN; ++n) {
                    acc[m][n] = __builtin_amdgcn_mfma_f32_16x16x32_bf16(
                        af[m][0], wf[n][0], acc[m][n], 0, 0, 0);
                    acc[m][n] = __builtin_amdgcn_mfma_f32_16x16x32_bf16(
                        af[m][1], wf[n][1], acc[m][n], 0, 0, 0);
                }
            __syncthreads();
        }
    }

    const bool dot = p.do_tanh != 0;
#pragma unroll
    for (int n = 0; n < FN; ++n) {
        const int col = col0 + wc * (BN / 2) + n * 16 + fr;
        float b = p.ba[col];
        if (p.bb) b += p.bb[col];
#pragma unroll
        for (int m = 0; m < FM; ++m) {
#pragma unroll
            for (int j = 0; j < 4; ++j) {
                const int r = row0 + wr * (BM / 2) + m * 16 + fk * 4 + j;
                float v = acc[m][n][j] + b;
                if (dot) v = tanhf(v);
                p.C[(size_t)r * p.ldc + col] = v;
                if (p.Cb) p.Cb[(size_t)r * p.ldcb + col] = f2b_rne(v);
            }
        }
    }
}

__global__ __launch_bounds__(256) void gemm1_k(GemmP p)
{
    __shared__ __align__(16) unsigned short As[128 * 64];
    __shared__ __align__(16) unsigned short Ws[64 * 64];
    gemm2p_body<128, 64>(p, blockIdx.x, As, Ws, threadIdx.x);
}

// ---------------- row log_softmax (bf16-in, fp32-out) -----------------------
__device__ __forceinline__ void logsoftmax_row_b16(
    const unsigned short* __restrict__ lb, float* __restrict__ op, int tid)
{
    const int lane = tid & 63;
    const int wv = tid >> 6;
    __shared__ float redm[4];
    __shared__ float reds[4];

    uint4 r[2];
    r[0] = *(const uint4*)&lb[tid * 8];
    r[1] = *(const uint4*)&lb[2048 + tid * 8];
    float v[16];
#pragma unroll
    for (int h = 0; h < 2; ++h)
#pragma unroll
        for (int j = 0; j < 4; ++j) {
            unsigned u = ((const unsigned*)&r[h])[j];
            v[h * 8 + 2 * j]     = __uint_as_float(u << 16);
            v[h * 8 + 2 * j + 1] = __uint_as_float(u & 0xFFFF0000u);
        }

    float m = v[0];
#pragma unroll
    for (int i = 1; i < 16; ++i) m = fmaxf(m, v[i]);
#pragma unroll
    for (int off = 32; off; off >>= 1) m = fmaxf(m, __shfl_xor(m, off));
    if (lane == 0) redm[wv] = m;
    __syncthreads();
    m = fmaxf(fmaxf(redm[0], redm[1]), fmaxf(redm[2], redm[3]));

    float s = 0.f;
#pragma unroll
    for (int i = 0; i < 16; ++i) s += expf(v[i] - m);
#pragma unroll
    for (int off = 32; off; off >>= 1) s += __shfl_xor(s, off);
    if (lane == 0) reds[wv] = s;
    __syncthreads();
    s = reds[0] + reds[1] + reds[2] + reds[3];

    const float lse = m + logf(s);
#pragma unroll
    for (int h = 0; h < 2; ++h) {
        float4 o0, o1;
        o0.x = v[h*8+0]-lse; o0.y = v[h*8+1]-lse; o0.z = v[h*8+2]-lse; o0.w = v[h*8+3]-lse;
        o1.x = v[h*8+4]-lse; o1.y = v[h*8+5]-lse; o1.z = v[h*8+6]-lse; o1.w = v[h*8+7]-lse;
        *(float4*)&op[h * 2048 + tid * 8]     = o0;
        *(float4*)&op[h * 2048 + tid * 8 + 4] = o1;
    }
}

// GEMM2 at 128x64/BK64 (blocks 0..511) + log_softmax rows (512..4607)
__global__ __launch_bounds__(256) void g2sm_k(
    GemmP p, float* __restrict__ out, const unsigned short* __restrict__ lb16)
{
    if (blockIdx.x < 512) {
        __shared__ __align__(16) unsigned short As[128 * 64];
        __shared__ __align__(16) unsigned short Ws[64 * 64];
        gemm2p_body<128, 64>(p, blockIdx.x, As, Ws, threadIdx.x);
    } else {
        const int row = blockIdx.x - 512;
        logsoftmax_row_b16(lb16 + (size_t)row * 4096,
                           out + (size_t)row * 4096, threadIdx.x);
    }
}

// ============ per-phase counted 256x256 GEMM (GEMM3) — locked ===============
// Schedule: p0 vmcnt(4);bar;rd af0,wfA;st A0(t+1);Q00 | p1 ...B1(t)... |
// p2 ...A1(t)... | p3 no-bar st A1(t+1) Q10. Tail 4/2/0. bf16 logits out.

__device__ __forceinline__ void stage_half8(
    const unsigned short* __restrict__ src, int ld, int base_rc, int tau, int h,
    unsigned short* lds, int wid, int lane, bool isA)
{
    unsigned short* dst = lds + (tau & 1) * 16384 + h * 8192 + wid * 1024;
    const int k0 = (tau & 15) << 6;
#pragma unroll
    for (int i = 0; i < 2; ++i) {
        int c = wid * 128 + i * 64 + lane;
        int ir = c >> 3, cc = c & 7;
        int grow = isA ? (base_rc + h * 64 + (ir & 63) + ((ir >> 6) << 7))
                       : (base_rc + h * 32 + (ir & 31) + ((ir >> 5) << 6));
        int gk = k0 + (((cc ^ ir) & 7) << 3);
        gload_lds16(src + (size_t)grow * ld + gk, dst + i * 512);
    }
}

__global__ __launch_bounds__(512, 2) void gemm8p(
    const unsigned short* __restrict__ Aa, const unsigned short* __restrict__ Ab,
    const unsigned short* __restrict__ Wa, const unsigned short* __restrict__ Wb,
    int lda, int ldw, const float* __restrict__ bias,
    unsigned short* __restrict__ Cb16, int ldc, int nx)
{
    constexpr int NT = 32;
    __shared__ __align__(16) unsigned short smem[65536];   // 128 KB
    unsigned short* As = smem;
    unsigned short* Bs = smem + 32768;

    int bid = blockIdx.x;
    bid = (bid & 7) * 32 + (bid >> 3);            // XCD swizzle (256 = 8*32)
    const int row0 = (bid / nx) * 256;
    const int col0 = (bid % nx) * 256;

    const int tid = threadIdx.x;
    const int wid = tid >> 6, lane = tid & 63;
    const int wr = wid >> 2, wc = wid & 3;        // 2 x 4 wave grid
    const int fr = lane & 15, fk = lane >> 4;
    const int ch0 = fk ^ (fr & 7);
    const int ch1 = ch0 ^ 4;

#define STA8(tau, h) stage_half8(((tau) < 16 ? Aa : Ab), lda, row0, (tau), (h), As, wid, lane, true)
#define STB8(tau, h) stage_half8(((tau) < 16 ? Wa : Wb), ldw, col0, (tau), (h), Bs, wid, lane, false)

#define LDAF(QM) { const unsigned short* Ap_ = Abase + (QM) * 8192;           \
    _Pragma("unroll") for (int mf = 0; mf < 4; ++mf) {                        \
        int ia = wr * 64 + mf * 16 + fr;                                      \
        af[mf][0] = *(const bf16x8*)&Ap_[ia * 64 + ch0 * 8];                  \
        af[mf][1] = *(const bf16x8*)&Ap_[ia * 64 + ch1 * 8]; } }

#define LDWF(QN, WF) { const unsigned short* Bp_ = Bbase + (QN) * 8192;       \
    _Pragma("unroll") for (int nf = 0; nf < 2; ++nf) {                        \
        int ib = wc * 32 + nf * 16 + fr;                                      \
        WF[nf][0] = *(const bf16x8*)&Bp_[ib * 64 + ch0 * 8];                  \
        WF[nf][1] = *(const bf16x8*)&Bp_[ib * 64 + ch1 * 8]; } }

#define MMQ(QM, QN, WF) {                                                     \
    __builtin_amdgcn_s_setprio(1);                                            \
    _Pragma("unroll") for (int mf = 0; mf < 4; ++mf)                          \
    _Pragma("unroll") for (int nf = 0; nf < 2; ++nf) {                        \
        acc[QM][QN][mf][nf] = __builtin_amdgcn_mfma_f32_16x16x32_bf16(        \
            af[mf][0], WF[nf][0], acc[QM][QN][mf][nf], 0, 0, 0);              \
        acc[QM][QN][mf][nf] = __builtin_amdgcn_mfma_f32_16x16x32_bf16(        \
            af[mf][1], WF[nf][1], acc[QM][QN][mf][nf], 0, 0, 0); }            \
    __builtin_amdgcn_s_setprio(0); }

    f32x4 acc[2][2][4][2] = {};
    bf16x8 af[4][2], wfA[2][2], wfB[2][2];

    // prologue: stage tile0's halves in consumption order A0,B0,B1,A1
    STA8(0, 0); STB8(0, 0); STB8(0, 1); STA8(0, 1);

    for (int t = 0; t < NT; ++t) {
        const unsigned short* Abase = As + (t & 1) * 16384;
        const unsigned short* Bbase = Bs + (t & 1) * 16384;
        const bool more = (t + 1 < NT);

        // p0: Q(0,0) — consumes A0(t),B0(t)
        asm volatile("s_waitcnt vmcnt(4)" ::: "memory");
        __builtin_amdgcn_s_barrier();
        LDAF(0); LDWF(0, wfA);
        if (more) STA8(t + 1, 0);
        MMQ(0, 0, wfA);

        // p1: Q(0,1) — consumes B1(t)
        if (more) { asm volatile("s_waitcnt vmcnt(4)" ::: "memory"); }
        else      { asm volatile("s_waitcnt vmcnt(2)" ::: "memory"); }
        __builtin_amdgcn_s_barrier();
        LDWF(1, wfB);
        if (more) STB8(t + 1, 0);
        MMQ(0, 1, wfB);

        // p2: Q(1,1) — consumes A1(t)
        if (more) { asm volatile("s_waitcnt vmcnt(4)" ::: "memory"); }
        else      { asm volatile("s_waitcnt vmcnt(0)" ::: "memory"); }
        __builtin_amdgcn_s_barrier();
        LDAF(1);
        if (more) STB8(t + 1, 1);
        MMQ(1, 1, wfB);

        // p3: Q(1,0) — zero ds_reads, no barrier
        if (more) STA8(t + 1, 1);
        MMQ(1, 0, wfA);
    }
#undef MMQ
#undef LDAF
#undef LDWF
#undef STA8
#undef STB8

    // epilogue: acc -> LDS (fp32, +bias, XOR de-conflict) -> bf16 ushort4
    float bv[2][2];
#pragma unroll
    for (int qn = 0; qn < 2; ++qn)
#pragma unroll
        for (int nf = 0; nf < 2; ++nf)
            bv[qn][nf] = bias[col0 + wc * 64 + qn * 32 + nf * 16 + fr];

    float* Ct = (float*)smem;                     // [128][256] fp32 = 128KB
    __syncthreads();
#pragma unroll
    for (int qm = 0; qm < 2; ++qm) {
        if (qm) __syncthreads();
#pragma unroll
        for (int qn = 0; qn < 2; ++qn)
#pragma unroll
            for (int nf = 0; nf < 2; ++nf) {
                const int col = wc * 64 + qn * 32 + nf * 16 + fr;
#pragma unroll
                for (int mf = 0; mf < 4; ++mf)
#pragma unroll
                    for (int j = 0; j < 4; ++j) {
                        int lr = wr * 64 + mf * 16 + fk * 4 + j;
                        int pc = col ^ (((lr >> 2) & 3) << 4);
                        Ct[lr * 256 + pc] = acc[qm][qn][mf][nf][j] + bv[qn][nf];
                    }
            }
        __syncthreads();
#pragma unroll
        for (int k = 0; k < 16; ++k) {
            int idx = k * 512 + tid;
            int lrow = idx >> 6, c4 = idx & 63;
            int pc4 = (c4 * 4) ^ (((lrow >> 2) & 3) << 4);
            int grow = row0 + qm * 64 + (lrow & 63) + ((lrow >> 6) << 7);
            float4 v = *(const float4*)&Ct[lrow * 256 + pc4];
            unsigned short o[4] = { f2b_rne(v.x), f2b_rne(v.y),
                                    f2b_rne(v.z), f2b_rne(v.w) };
            *(ushort4*)&Cb16[(size_t)grow * ldc + col0 + c4 * 4] =
                *(const ushort4*)o;
        }
    }
}

// ============================================================================
extern "C" void kernel_launch(void* const* d_in, const int* in_sizes, int n_in,
                              void* d_out, int out_size, void* d_ws, size_t ws_size,
                              hipStream_t stream)
{
    (void)in_sizes; (void)n_in; (void)out_size; (void)ws_size;

    const float* input  = (const float*)d_in[0];
    const float* hidden = (const float*)d_in[1];
    const float* b_ih0  = (const float*)d_in[4];
    const float* b_hh0  = (const float*)d_in[5];
    const float* b_ih1  = (const float*)d_in[8];
    const float* b_hh1  = (const float*)d_in[9];
    const float* b_out  = (const float*)d_in[11];

    float* out = (float*)d_out;                    // [4096,4096]
    float* h0  = out + (size_t)4096 * 4096;
    float* h1  = h0 + (size_t)4096 * 1024;

    unsigned short* xb    = (unsigned short*)d_ws;
    unsigned short* hidb  = xb    + (size_t)4096 * 1024;
    unsigned short* h0b   = hidb  + (size_t)2 * 4096 * 1024;
    unsigned short* Wih0b = h0b   + (size_t)4096 * 1024;
    unsigned short* Whh0b = Wih0b + (size_t)1024 * 1024;
    unsigned short* Wih1b = Whh0b + (size_t)1024 * 1024;
    unsigned short* Whh1b = Wih1b + (size_t)1024 * 1024;
    unsigned short* Woutb = Whh1b + (size_t)1024 * 1024;
    unsigned short* lb16  = Woutb + (size_t)4096 * 2048;   // bf16 logits, 32MB
    unsigned short* hid0b = hidb;
    unsigned short* hid1b = hidb + (size_t)4096 * 1024;

    // one standalone conversion pass
    CvtArgs ca;
    ca.seg[0] = { input,                 xb,    524288u };
    ca.seg[1] = { hidden,                hidb, 1048576u };
    ca.seg[2] = { (const float*)d_in[2], Wih0b, 131072u };
    ca.seg[3] = { (const float*)d_in[3], Whh0b, 131072u };
    ca.seg[4] = { (const float*)d_in[6], Wih1b, 131072u };
    ca.seg[5] = { (const float*)d_in[7], Whh1b, 131072u };
    ca.seg[6] = { (const float*)d_in[10],Woutb, 1048576u };
    ca.seg[7] = { nullptr, nullptr, 0u };
    hipLaunchKernelGGL(f2b_multi, dim3(12288), dim3(256), 0, stream, ca);

    // GEMM1: h0 = tanh(x@Wih0^T + hid0@Whh0^T + b), 128x64/BK64, 512 blocks
    GemmP p1;
    p1.Aa = xb;    p1.Ab = hid0b; p1.lda = 1024;
    p1.Wa = Wih0b; p1.Wb = Whh0b; p1.ldw = 1024;
    p1.ba = b_ih0; p1.bb = b_hh0;
    p1.C = h0; p1.ldc = 1024; p1.Cb = h0b; p1.ldcb = 1024;
    p1.nx = 16; p1.nb = 512; p1.do_tanh = 1;
    hipLaunchKernelGGL(gemm1_k, dim3(512), dim3(256), 0, stream, p1);

    // GEMM3: bf16 logits = x@W_out[:,:1024]^T + h0@W_out[:,1024:]^T + b_out
    hipLaunchKernelGGL(gemm8p, dim3(256), dim3(512), 0, stream,
                       xb, h0b, Woutb, Woutb + 1024, 1024, 2048,
                       b_out, lb16, 4096, 16);

    // GEMM2 at 128x64/BK64 (512 blocks) + log_softmax (4096 rows)
    GemmP p2;
    p2.Aa = h0b;   p2.Ab = hid1b; p2.lda = 1024;
    p2.Wa = Wih1b; p2.Wb = Whh1b; p2.ldw = 1024;
    p2.ba = b_ih1; p2.bb = b_hh1;
    p2.C = h1; p2.ldc = 1024; p2.Cb = nullptr; p2.ldcb = 0;
    p2.nx = 16; p2.nb = 512; p2.do_tanh = 1;
    hipLaunchKernelGGL(g2sm_k, dim3(4608), dim3(256), 0, stream, p2, out, lb16);
}